// Round 1
// baseline (181.639 us; speedup 1.0000x reference)
//
#include <hip/hip_runtime.h>
#include <cmath>

// GRU-D cell: B=16384, F=U=512.
// Strategy: bf16 MFMA GEMMs (fp32 vector would be >330us; bf16 MFMA ~60us).
//   prep:  xd, hd elementwise -> A1 = [xd|hd] bf16 (B x 1024)
//   pack:  weights -> bf16 B^T (N x K) layouts: Wzr (1024x1024), Wht (512x1024)
//   gemm<0>: A1 @ Wzr -> sigmoid epilogue -> Z (fp32), RH = r*hd (bf16)
//   gemm<1>: [xd|RH] @ Wht -> tanh epilogue, recompute hd fp32, blend -> out

typedef __bf16 bf16x8 __attribute__((ext_vector_type(8)));
typedef __bf16 bf16x4 __attribute__((ext_vector_type(4)));
typedef float f32x4 __attribute__((ext_vector_type(4)));

typedef __attribute__((address_space(3))) void lds_vp;
typedef const __attribute__((address_space(1))) void g_vp;

__device__ __forceinline__ float sigmoidf_(float x) { return 1.f / (1.f + expf(-x)); }

// ---------------- prep: elementwise decay + bf16 pack ----------------
__global__ __launch_bounds__(256) void prep_k(
    const float* __restrict__ inp, const float* __restrict__ h_prev,
    const float* __restrict__ gxd, const float* __restrict__ ghd,
    const float* __restrict__ mimp, __bf16* __restrict__ A1) {
  int idx = blockIdx.x * 256 + threadIdx.x;   // one thread = 4 columns
  int row = idx >> 7;
  int c4 = (idx & 127) << 2;
  const float4 x  = *(const float4*)(inp + (size_t)row * 1536 + c4);
  const float4 mm = *(const float4*)(inp + (size_t)row * 1536 + 512 + c4);
  const float4 dt = *(const float4*)(inp + (size_t)row * 1536 + 1024 + c4);
  const float4 gx = *(const float4*)(gxd + c4);
  const float4 gh = *(const float4*)(ghd + c4);
  const float4 mi = *(const float4*)(mimp + c4);
  const float4 hp = *(const float4*)(h_prev + (size_t)row * 512 + c4);
  bf16x4 xo, ho;
#pragma unroll
  for (int j = 0; j < 4; ++j) {
    float xx = ((const float*)&x)[j];
    float m  = ((const float*)&mm)[j];
    float d  = ((const float*)&dt)[j];
    float g  = expf(-fmaxf(0.f, ((const float*)&gx)[j]) * d);
    float xd = m * xx + (1.f - m) * (g * xx + (1.f - g) * ((const float*)&mi)[j]);
    float gg = expf(-fmaxf(0.f, ((const float*)&gh)[j]) * d);
    float hd = gg * ((const float*)&hp)[j];
    xo[j] = (__bf16)xd;
    ho[j] = (__bf16)hd;
  }
  *(bf16x4*)(A1 + (size_t)row * 1024 + c4) = xo;
  *(bf16x4*)(A1 + (size_t)row * 1024 + 512 + c4) = ho;
}

// ---------------- pack: weights -> B^T bf16 ----------------
__global__ __launch_bounds__(256) void pack_k(
    const float* __restrict__ Wz, const float* __restrict__ Uz,
    const float* __restrict__ Wr, const float* __restrict__ Ur,
    const float* __restrict__ Wh, const float* __restrict__ Uh,
    __bf16* __restrict__ Wzr, __bf16* __restrict__ Wht) {
  int id = blockIdx.x * 256 + threadIdx.x;
  if (id < 1024 * 1024) {
    int n = id >> 10, k = id & 1023;
    float v;
    if (n < 512) v = (k < 512) ? Wz[k * 512 + n] : Uz[(k - 512) * 512 + n];
    else         v = (k < 512) ? Wr[k * 512 + (n - 512)] : Ur[(k - 512) * 512 + (n - 512)];
    Wzr[id] = (__bf16)v;
  } else {
    int id2 = id - 1024 * 1024;
    int n = id2 >> 10, k = id2 & 1023;
    float v = (k < 512) ? Wh[k * 512 + n] : Uh[(k - 512) * 512 + n];
    Wht[id2] = (__bf16)v;
  }
}

// ---------------- GEMM: 128x128 tile, BK=64, 4 waves 2x2, 16x16x32 bf16 ----------------
__device__ __forceinline__ void stage128(const char* g, int ldb, char* lds, int tid) {
  int wave = tid >> 6;
#pragma unroll
  for (int i = 0; i < 4; ++i) {
    int o = (i * 256 + tid) * 16;        // linear byte offset in 16KB tile
    int r = o >> 7, c = o & 127;         // 128B per row
    __builtin_amdgcn_global_load_lds(
        (g_vp*)(g + (size_t)r * ldb + c),
        (lds_vp*)(lds + (i * 4 + wave) * 1024),   // wave-uniform base + lane*16
        16, 0, 0);
  }
}

template <int MODE>
__global__ __launch_bounds__(256) void gemm_k(
    const __bf16* __restrict__ A1, const __bf16* __restrict__ RH,
    const __bf16* __restrict__ Bt,
    float* __restrict__ Z, __bf16* __restrict__ RHout,
    const float* __restrict__ bias_a, const float* __restrict__ bias_b,
    const float* __restrict__ inp, const float* __restrict__ h_prev,
    const float* __restrict__ ghd, float* __restrict__ out) {
  __shared__ __bf16 As[128][64];
  __shared__ __bf16 Bs[128][64];
  constexpr int NBN = (MODE == 0) ? 8 : 4;
  int bid = blockIdx.x;
  int bm = bid / NBN, bn = bid % NBN;
  int tid = threadIdx.x;
  int lane = tid & 63, wid = tid >> 6;
  int wm = wid >> 1, wn = wid & 1;

  f32x4 acc[4][4] = {};

  for (int k0 = 0; k0 < 1024; k0 += 64) {
    const char* Ag;
    int lda;
    if (MODE == 0) {
      Ag = (const char*)(A1 + (size_t)bm * 128 * 1024 + k0);
      lda = 2048;
    } else {
      if (k0 < 512) {
        Ag = (const char*)(A1 + (size_t)bm * 128 * 1024 + k0);
        lda = 2048;
      } else {
        Ag = (const char*)(RH + (size_t)bm * 128 * 512 + (k0 - 512));
        lda = 1024;
      }
    }
    stage128(Ag, lda, (char*)&As[0][0], tid);
    stage128((const char*)(Bt + (size_t)bn * 128 * 1024 + k0), 2048, (char*)&Bs[0][0], tid);
    __syncthreads();

#pragma unroll
    for (int kk = 0; kk < 2; ++kk) {
      bf16x8 a[4], b[4];
#pragma unroll
      for (int m = 0; m < 4; ++m)
        a[m] = *(const bf16x8*)&As[wm * 64 + m * 16 + (lane & 15)][kk * 32 + (lane >> 4) * 8];
#pragma unroll
      for (int n = 0; n < 4; ++n)
        b[n] = *(const bf16x8*)&Bs[wn * 64 + n * 16 + (lane & 15)][kk * 32 + (lane >> 4) * 8];
#pragma unroll
      for (int m = 0; m < 4; ++m)
#pragma unroll
        for (int n = 0; n < 4; ++n)
          acc[m][n] = __builtin_amdgcn_mfma_f32_16x16x32_bf16(a[m], b[n], acc[m][n], 0, 0, 0);
    }
    __syncthreads();
  }

  // epilogue
  int col16 = lane & 15, rgrp = lane >> 4;
#pragma unroll
  for (int m = 0; m < 4; ++m) {
    int grow0 = bm * 128 + wm * 64 + m * 16 + rgrp * 4;
#pragma unroll
    for (int n = 0; n < 4; ++n) {
      int gcol = bn * 128 + wn * 64 + n * 16 + col16;
#pragma unroll
      for (int j = 0; j < 4; ++j) {
        int grow = grow0 + j;
        float v = acc[m][n][j];
        if constexpr (MODE == 0) {
          if (gcol < 512) {  // block-uniform branch (BN=128 divides 512)
            float z = sigmoidf_(v + bias_a[gcol]);
            Z[(size_t)grow * 512 + gcol] = z;
          } else {
            int c = gcol - 512;
            float r = sigmoidf_(v + bias_b[c]);
            float hd = (float)A1[(size_t)grow * 1024 + 512 + c];
            RHout[(size_t)grow * 512 + c] = (__bf16)(r * hd);
          }
        } else {
          float hh = tanhf(v + bias_a[gcol]);
          float d = inp[(size_t)grow * 1536 + 1024 + gcol];
          float gg = expf(-fmaxf(0.f, ghd[gcol]) * d);
          float hd = gg * h_prev[(size_t)grow * 512 + gcol];
          float z = Z[(size_t)grow * 512 + gcol];
          out[(size_t)grow * 512 + gcol] = (1.f - z) * hd + z * hh;
        }
      }
    }
  }
}

// ---------------- launch ----------------
extern "C" void kernel_launch(void* const* d_in, const int* in_sizes, int n_in,
                              void* d_out, int out_size, void* d_ws, size_t ws_size,
                              hipStream_t stream) {
  const float* inputs = (const float*)d_in[0];
  const float* h_prev = (const float*)d_in[1];
  const float* W_z = (const float*)d_in[2];
  const float* U_z = (const float*)d_in[3];
  const float* b_z = (const float*)d_in[4];
  const float* W_r = (const float*)d_in[5];
  const float* U_r = (const float*)d_in[6];
  const float* b_r = (const float*)d_in[7];
  const float* W_h = (const float*)d_in[8];
  const float* U_h = (const float*)d_in[9];
  const float* b_h = (const float*)d_in[10];
  const float* gxd = (const float*)d_in[11];
  const float* ghd = (const float*)d_in[12];
  const float* mimp = (const float*)d_in[13];
  float* out = (float*)d_out;

  char* ws = (char*)d_ws;
  __bf16* A1  = (__bf16*)(ws);                       // 16384x1024 bf16 = 32MB
  __bf16* RH  = (__bf16*)(ws + 33554432);            // 16384x512 bf16 = 16MB
  float*  Z   = (float*)(ws + 50331648);             // 16384x512 f32  = 32MB
  __bf16* Wzr = (__bf16*)(ws + 83886080);            // 1024x1024 bf16 = 2MB
  __bf16* Wht = (__bf16*)(ws + 85983232);            // 512x1024 bf16  = 1MB

  prep_k<<<8192, 256, 0, stream>>>(inputs, h_prev, gxd, ghd, mimp, A1);
  pack_k<<<6144, 256, 0, stream>>>(W_z, U_z, W_r, U_r, W_h, U_h, Wzr, Wht);
  gemm_k<0><<<1024, 256, 0, stream>>>(A1, RH, Wzr, Z, RH, b_z, b_r,
                                      nullptr, nullptr, nullptr, nullptr);
  gemm_k<1><<<512, 256, 0, stream>>>(A1, RH, Wht, Z, nullptr, b_h, nullptr,
                                     inputs, h_prev, ghd, out);
}

// Round 2
// 153.141 us; speedup vs baseline: 1.1861x; 1.1861x over previous
//
#include <hip/hip_runtime.h>
#include <cmath>

// GRU-D cell: B=16384, F=U=512.
//   prep:  xd, hd elementwise -> A1 = [xd|hd] bf16 (B x 1024)
//   pack:  weights -> bf16 B^T (N x K): Wzr (1024x1024), Wht (512x1024)
//   gemm8<0>: A1 @ Wzr -> sigmoid -> Zb (bf16), RH = r*hd (bf16)
//   gemm8<1>: [xd|RH] @ Wht -> tanh, blend with Zb, hd from A1 -> out
// gemm8 = 256x256 tile, BK=64, 8 waves (2Mx4N), 8-phase/2-Ktile schedule,
// counted vmcnt(6), XOR-16B LDS swizzle, raw s_barrier, setprio MFMA clusters.

typedef __bf16 bf16x8 __attribute__((ext_vector_type(8)));
typedef __bf16 bf16x4 __attribute__((ext_vector_type(4)));
typedef float f32x4 __attribute__((ext_vector_type(4)));

typedef __attribute__((address_space(3))) void lds_vp;
typedef const __attribute__((address_space(1))) void g_vp;

#define BAR() __builtin_amdgcn_s_barrier()
#define LGKM0() asm volatile("s_waitcnt lgkmcnt(0)" ::: "memory")
#define VMC(N) asm volatile("s_waitcnt vmcnt(" N ")" ::: "memory")

__device__ __forceinline__ float sigmoidf_(float x) { return 1.f / (1.f + expf(-x)); }

// ---------------- prep ----------------
__global__ __launch_bounds__(256) void prep_k(
    const float* __restrict__ inp, const float* __restrict__ h_prev,
    const float* __restrict__ gxd, const float* __restrict__ ghd,
    const float* __restrict__ mimp, __bf16* __restrict__ A1) {
  int idx = blockIdx.x * 256 + threadIdx.x;
  int row = idx >> 7;
  int c4 = (idx & 127) << 2;
  const float4 x  = *(const float4*)(inp + (size_t)row * 1536 + c4);
  const float4 mm = *(const float4*)(inp + (size_t)row * 1536 + 512 + c4);
  const float4 dt = *(const float4*)(inp + (size_t)row * 1536 + 1024 + c4);
  const float4 gx = *(const float4*)(gxd + c4);
  const float4 gh = *(const float4*)(ghd + c4);
  const float4 mi = *(const float4*)(mimp + c4);
  const float4 hp = *(const float4*)(h_prev + (size_t)row * 512 + c4);
  bf16x4 xo, ho;
#pragma unroll
  for (int j = 0; j < 4; ++j) {
    float xx = ((const float*)&x)[j];
    float m  = ((const float*)&mm)[j];
    float d  = ((const float*)&dt)[j];
    float g  = expf(-fmaxf(0.f, ((const float*)&gx)[j]) * d);
    float xd = m * xx + (1.f - m) * (g * xx + (1.f - g) * ((const float*)&mi)[j]);
    float gg = expf(-fmaxf(0.f, ((const float*)&gh)[j]) * d);
    float hd = gg * ((const float*)&hp)[j];
    xo[j] = (__bf16)xd;
    ho[j] = (__bf16)hd;
  }
  *(bf16x4*)(A1 + (size_t)row * 1024 + c4) = xo;
  *(bf16x4*)(A1 + (size_t)row * 1024 + 512 + c4) = ho;
}

// ---------------- pack ----------------
__global__ __launch_bounds__(256) void pack_k(
    const float* __restrict__ Wz, const float* __restrict__ Uz,
    const float* __restrict__ Wr, const float* __restrict__ Ur,
    const float* __restrict__ Wh, const float* __restrict__ Uh,
    __bf16* __restrict__ Wzr, __bf16* __restrict__ Wht) {
  int id = blockIdx.x * 256 + threadIdx.x;
  if (id < 1024 * 1024) {
    int n = id >> 10, k = id & 1023;
    float v;
    if (n < 512) v = (k < 512) ? Wz[k * 512 + n] : Uz[(k - 512) * 512 + n];
    else         v = (k < 512) ? Wr[k * 512 + (n - 512)] : Ur[(k - 512) * 512 + (n - 512)];
    Wzr[id] = (__bf16)v;
  } else {
    int id2 = id - 1024 * 1024;
    int n = id2 >> 10, k = id2 & 1023;
    float v = (k < 512) ? Wh[k * 512 + n] : Uh[(k - 512) * 512 + n];
    Wht[id2] = (__bf16)v;
  }
}

// ---------------- 8-phase GEMM ----------------
// stage one 8KB quarter: 8 waves x 8 rows x 128B, linear LDS dest,
// inverse-swizzled global source (LDS[r][o] holds global (r, o^((r&7)<<4))).
__device__ __forceinline__ void stage_q(const char* g, int ldb, char* ldst,
                                        int rowbase, int lane) {
  int r = rowbase + (lane >> 3);
  int c = (((lane & 7) ^ (lane >> 3)) << 4);
  __builtin_amdgcn_global_load_lds((g_vp*)(g + (size_t)r * ldb + c),
                                   (lds_vp*)(ldst + rowbase * 128), 16, 0, 0);
}

#define MFMA16(MB, NB, BF)                                                     \
  __builtin_amdgcn_s_setprio(1);                                               \
  _Pragma("unroll") for (int mi = 0; mi < 4; ++mi)                             \
  _Pragma("unroll") for (int ni = 0; ni < 2; ++ni) {                           \
    acc[(MB) + mi][(NB) + ni] = __builtin_amdgcn_mfma_f32_16x16x32_bf16(       \
        af[mi * 2 + 0], BF[ni * 2 + 0], acc[(MB) + mi][(NB) + ni], 0, 0, 0);   \
    acc[(MB) + mi][(NB) + ni] = __builtin_amdgcn_mfma_f32_16x16x32_bf16(       \
        af[mi * 2 + 1], BF[ni * 2 + 1], acc[(MB) + mi][(NB) + ni], 0, 0, 0);   \
  }                                                                            \
  __builtin_amdgcn_s_setprio(0);

template <int MODE>
__global__ __launch_bounds__(512, 2) void gemm8_k(
    const __bf16* __restrict__ A1, const __bf16* __restrict__ RH,
    const __bf16* __restrict__ Bt,
    __bf16* __restrict__ Zb, __bf16* __restrict__ RHout,
    const float* __restrict__ bza, const float* __restrict__ bzb,
    float* __restrict__ out) {
  __shared__ char lds[131072];  // [buf][A 32KB | B 32KB]
  constexpr int NT = 16;
  constexpr int NBN = (MODE == 0) ? 4 : 2;
  constexpr int CPX = ((MODE == 0) ? 256 : 128) / 8;
  int bid = blockIdx.x;
  int swz = (bid & 7) * CPX + (bid >> 3);   // bijective XCD swizzle
  int bm = swz / NBN, bn = swz % NBN;
  int tid = threadIdx.x, lane = tid & 63, wid = tid >> 6;
  int wm = wid >> 2, wn = wid & 3;

  auto stageA = [&](int t, int half) {  // half 0: rows{0-63,128-191}, 1: +64
    const char* g;
    int ldb;
    if (MODE == 0 || t < 8) {
      g = (const char*)A1 + (size_t)bm * 256 * 2048 + t * 128;
      ldb = 2048;
    } else {
      g = (const char*)RH + (size_t)bm * 256 * 1024 + (t - 8) * 128;
      ldb = 1024;
    }
    char* ldst = lds + ((t & 1) ? 65536 : 0);
    int rb = half * 64 + wid * 8;
    stage_q(g, ldb, ldst, rb, lane);
    stage_q(g, ldb, ldst, rb + 128, lane);
  };
  auto stageB = [&](int t, int nhalf) {  // nhalf 0: n0-1 rows, 1: n2-3 rows
    const char* g = (const char*)Bt + (size_t)bn * 256 * 2048 + t * 128;
    char* ldst = lds + ((t & 1) ? 65536 : 0) + 32768;
    int rb = (wid & 3) * 8 + (wid >> 2) * 64 + nhalf * 32;
    stage_q(g, 2048, ldst, rb, lane);
    stage_q(g, 2048, ldst, rb + 128, lane);
  };

  // per-thread loop-invariant ds_read bases (swizzled col bytes for kk=0/1)
  int cb0 = (((lane >> 4) << 4)) ^ ((lane & 7) << 4);
  int cb1 = (((lane >> 4) << 4) + 64) ^ ((lane & 7) << 4);
  const char* A_base = lds + wm * 16384 + (lane & 15) * 128;
  const char* B_base = lds + 32768 + wn * 8192 + (lane & 15) * 128;
  const char* A0k0 = A_base + cb0;
  const char* A0k1 = A_base + cb1;
  const char* B0k0 = B_base + cb0;
  const char* B0k1 = B_base + cb1;

  f32x4 acc[8][4] = {};

  // prologue: tile0 full, tile1 all but Bn01
  stageA(0, 0); stageB(0, 1); stageA(0, 1); stageB(0, 0);
  stageA(1, 0); stageB(1, 1); stageA(1, 1);
  VMC("6");
  BAR();

  for (int t = 0; t < NT; ++t) {
    int p = t & 1;
    const char* ak0 = p ? A0k0 + 65536 : A0k0;
    const char* ak1 = p ? A0k1 + 65536 : A0k1;
    const char* bk0 = p ? B0k0 + 65536 : B0k0;
    const char* bk1 = p ? B0k1 + 65536 : B0k1;

    bf16x8 af[8], b01[4], b23[4];
    // ---- phase 1: A(m0-3), B(n0-1); stage Bn01(t+1) -> other buf ----
#pragma unroll
    for (int mi = 0; mi < 4; ++mi) {
      af[mi * 2 + 0] = *(const bf16x8*)(ak0 + mi * 2048);
      af[mi * 2 + 1] = *(const bf16x8*)(ak1 + mi * 2048);
    }
#pragma unroll
    for (int ni = 0; ni < 2; ++ni) {
      b01[ni * 2 + 0] = *(const bf16x8*)(bk0 + ni * 2048);
      b01[ni * 2 + 1] = *(const bf16x8*)(bk1 + ni * 2048);
    }
    if (t + 1 < NT) stageB(t + 1, 0);
    BAR(); LGKM0();
    MFMA16(0, 0, b01);
    BAR();
    // ---- phase 2: B(n2-3); stage A q02(t+2) -> this buf ----
#pragma unroll
    for (int ni = 0; ni < 2; ++ni) {
      b23[ni * 2 + 0] = *(const bf16x8*)(bk0 + (2 + ni) * 2048);
      b23[ni * 2 + 1] = *(const bf16x8*)(bk1 + (2 + ni) * 2048);
    }
    if (t + 2 < NT) stageA(t + 2, 0);
    BAR(); LGKM0();
    MFMA16(0, 2, b23);
    BAR();
    // ---- phase 3: A(m4-7); stage Bn23(t+2) -> this buf ----
#pragma unroll
    for (int mi = 0; mi < 4; ++mi) {
      af[mi * 2 + 0] = *(const bf16x8*)(ak0 + (4 + mi) * 2048);
      af[mi * 2 + 1] = *(const bf16x8*)(ak1 + (4 + mi) * 2048);
    }
    if (t + 2 < NT) stageB(t + 2, 1);
    BAR(); LGKM0();
    MFMA16(4, 2, b23);
    BAR();
    // ---- phase 4: B(n0-1) re-read; stage A q13(t+2); counted vmcnt ----
#pragma unroll
    for (int ni = 0; ni < 2; ++ni) {
      b01[ni * 2 + 0] = *(const bf16x8*)(bk0 + ni * 2048);
      b01[ni * 2 + 1] = *(const bf16x8*)(bk1 + ni * 2048);
    }
    if (t + 2 < NT) stageA(t + 2, 1);
    if (t < NT - 2) { VMC("6"); } else if (t == NT - 2) { VMC("0"); }
    BAR(); LGKM0();
    MFMA16(4, 0, b01);
    BAR();
  }

  // ---------------- epilogue ----------------
  int col16 = lane & 15, rgrp = lane >> 4;
#pragma unroll
  for (int m = 0; m < 8; ++m) {
    int grow0 = bm * 256 + wm * 128 + m * 16 + rgrp * 4;
#pragma unroll
    for (int n = 0; n < 4; ++n) {
      int gc = bn * 256 + wn * 64 + n * 16 + col16;
      if constexpr (MODE == 0) {
        if (bn < 2) {  // z columns (block-uniform)
          float b = bza[gc];
#pragma unroll
          for (int j = 0; j < 4; ++j) {
            float z = sigmoidf_(acc[m][n][j] + b);
            Zb[(size_t)(grow0 + j) * 512 + gc] = (__bf16)z;
          }
        } else {       // r columns
          int c = gc - 512;
          float b = bzb[c];
#pragma unroll
          for (int j = 0; j < 4; ++j) {
            int grow = grow0 + j;
            float r = sigmoidf_(acc[m][n][j] + b);
            float hd = (float)A1[(size_t)grow * 1024 + 512 + c];
            RHout[(size_t)grow * 512 + c] = (__bf16)(r * hd);
          }
        }
      } else {
        float b = bza[gc];
#pragma unroll
        for (int j = 0; j < 4; ++j) {
          int grow = grow0 + j;
          float hh = tanhf(acc[m][n][j] + b);
          float hd = (float)A1[(size_t)grow * 1024 + 512 + gc];
          float z = (float)Zb[(size_t)grow * 512 + gc];
          out[(size_t)grow * 512 + gc] = (1.f - z) * hd + z * hh;
        }
      }
    }
  }
}

// ---------------- launch ----------------
extern "C" void kernel_launch(void* const* d_in, const int* in_sizes, int n_in,
                              void* d_out, int out_size, void* d_ws, size_t ws_size,
                              hipStream_t stream) {
  const float* inputs = (const float*)d_in[0];
  const float* h_prev = (const float*)d_in[1];
  const float* W_z = (const float*)d_in[2];
  const float* U_z = (const float*)d_in[3];
  const float* b_z = (const float*)d_in[4];
  const float* W_r = (const float*)d_in[5];
  const float* U_r = (const float*)d_in[6];
  const float* b_r = (const float*)d_in[7];
  const float* W_h = (const float*)d_in[8];
  const float* U_h = (const float*)d_in[9];
  const float* b_h = (const float*)d_in[10];
  const float* gxd = (const float*)d_in[11];
  const float* ghd = (const float*)d_in[12];
  const float* mimp = (const float*)d_in[13];
  float* out = (float*)d_out;

  char* ws = (char*)d_ws;
  __bf16* A1  = (__bf16*)(ws);                  // 16384x1024 bf16 = 32MB
  __bf16* RH  = (__bf16*)(ws + 33554432);       // 16384x512 bf16 = 16MB
  __bf16* Zb  = (__bf16*)(ws + 50331648);       // 16384x512 bf16 = 16MB
  __bf16* Wzr = (__bf16*)(ws + 67108864);       // 1024x1024 bf16 = 2MB
  __bf16* Wht = (__bf16*)(ws + 69206016);       // 512x1024 bf16  = 1MB

  prep_k<<<8192, 256, 0, stream>>>(inputs, h_prev, gxd, ghd, mimp, A1);
  pack_k<<<6144, 256, 0, stream>>>(W_z, U_z, W_r, U_r, W_h, U_h, Wzr, Wht);
  gemm8_k<0><<<256, 512, 0, stream>>>(A1, RH, Wzr, Zb, RH, b_z, b_r, nullptr);
  gemm8_k<1><<<128, 512, 0, stream>>>(A1, RH, Wht, Zb, nullptr, b_h, nullptr, out);
}